// Round 8
// baseline (125.749 us; speedup 1.0000x reference)
//
#include <hip/hip_runtime.h>
#include <hip/hip_bf16.h>

#define T_SEQ   2048
#define EMBED   1024
#define HD      64
#define NHEADS  16
#define NBH     32            // B*H
// 0.125 * log2(e): fold softmax scale AND exp->exp2 conversion into Q
#define QSCALE  0.18033688011112042f

typedef __attribute__((ext_vector_type(8))) short short8;
typedef __attribute__((ext_vector_type(4))) float f32x4;
typedef __attribute__((ext_vector_type(16))) float f32x16;
typedef __attribute__((ext_vector_type(2))) unsigned int uint2v;
typedef __attribute__((ext_vector_type(4))) unsigned int uint4v;

#if __has_builtin(__builtin_amdgcn_exp2f)
#define EXP2F __builtin_amdgcn_exp2f   // raw v_exp_f32
#else
#define EXP2F exp2f
#endif

// round-half-up bf16
__device__ __forceinline__ ushort bf16r(float f) {
  union { float f; unsigned u; } v; v.f = f;
  return (ushort)((v.u + 0x8000u) >> 16);
}

// pack two floats to bf16x2 (a in low half)
__device__ __forceinline__ unsigned pk2bf_perm(float a, float b) {
  union { float f; unsigned u; } ua, ub; ua.f = a; ub.f = b;
  return __builtin_amdgcn_perm(ub.u + 0x8000u, ua.u + 0x8000u, 0x07060302u);
}
#if __has_builtin(__builtin_amdgcn_cvt_pk_bf16_f32)
typedef __attribute__((ext_vector_type(2))) __bf16 bf16x2;
__device__ __forceinline__ unsigned pkbf(float a, float b) {
  union { bf16x2 v; unsigned u; } c;
  c.v = __builtin_amdgcn_cvt_pk_bf16_f32(a, b);
  return c.u;
}
#else
#define pkbf pk2bf_perm
#endif

// permlane32_swap: new_a = {a_lo, b_lo}, new_b = {a_hi, b_hi} (32-lane halves)
__device__ __forceinline__ uint2v pl32swap(unsigned a, unsigned b) {
#if __has_builtin(__builtin_amdgcn_permlane32_swap)
  return __builtin_amdgcn_permlane32_swap(a, b, false, false);
#else
  asm("v_permlane32_swap_b32 %0, %1" : "+v"(a), "+v"(b));
  return (uint2v){a, b};
#endif
}

// async 16B global->LDS DMA; HW dest = wave-uniform base + lane*16
__device__ __forceinline__ void async16(const ushort* g, ushort* l) {
  __builtin_amdgcn_global_load_lds(
      (const __attribute__((address_space(1))) unsigned int*)g,
      (__attribute__((address_space(3))) unsigned int*)l, 16, 0, 0);
}

// ---------------------------------------------------------------------------
// Kernel 0: W prep: W[d][c] fp32 -> Wg bf16 transposed [c][d], XOR-chunk
// swizzled (phys 8-short chunk = (d>>3) ^ (c&7)).
// ---------------------------------------------------------------------------
__global__ __launch_bounds__(256) void prep_w(const float* __restrict__ W,
                                              ushort* __restrict__ Wg) {
  const int i = blockIdx.x * 256 + threadIdx.x;    // 48 x 256 = 12288
  const int d = i / 192, c = i - d * 192;
  const int phys = c * 64 + (((d >> 3) ^ (c & 7)) << 3) + (d & 7);
  Wg[phys] = bf16r(W[i]);
}

// ---------------------------------------------------------------------------
// Kernel 1: QKV projection via MFMA 16x16x32 bf16 (R3 proven version).
// Q/K paths use SWAPPED operands: acc = mfma(W_frag, x_frag) so C rows =
// out-channel d, cols = t -> one 8-B store per nt + aligned f32x4 bias load.
// ---------------------------------------------------------------------------
__global__ __launch_bounds__(256) void qkv_proj(
    const float* __restrict__ x, const ushort* __restrict__ Wg,
    const float* __restrict__ bias,
    ushort* __restrict__ Qws, ushort* __restrict__ Kws,
    ushort* __restrict__ Vtws) {
  __shared__ ushort WtL[192 * 64];
  __shared__ __attribute__((aligned(16))) float bl[192];

  const int bx = blockIdx.x;         // 1024 = 2b x 16h x 32 t-tiles
  const int b  = bx >> 9;
  const int h  = (bx >> 5) & 15;
  const int t0 = (bx & 31) * 64;
  const int tid = threadIdx.x;
  const int wave = tid >> 6, lane = tid & 63;
  const int quad = lane >> 4, n16 = lane & 15;

  const int trow = t0 + wave * 16 + n16;
  const float* xr = x + ((size_t)(b * T_SEQ + trow)) * EMBED + h * HD;
  short8 xa[2];
#pragma unroll
  for (int ks = 0; ks < 2; ks++) {
    f32x4 v0 = *(const f32x4*)(xr + ks * 32 + quad * 8);
    f32x4 v1 = *(const f32x4*)(xr + ks * 32 + quad * 8 + 4);
    short8 f;
    ((unsigned*)&f)[0] = pkbf(v0[0], v0[1]);
    ((unsigned*)&f)[1] = pkbf(v0[2], v0[3]);
    ((unsigned*)&f)[2] = pkbf(v1[0], v1[1]);
    ((unsigned*)&f)[3] = pkbf(v1[2], v1[3]);
    xa[ks] = f;
  }

#pragma unroll
  for (int it = 0; it < 6; it++)
    async16(Wg + it * 2048 + tid * 8, WtL + it * 2048 + wave * 512);
  if (tid < 192) bl[tid] = bias[tid];
  __syncthreads();

  const int bh = b * NHEADS + h;
  const size_t qkbase = (size_t)bh * T_SEQ * HD;
  const int tw = t0 + wave * 16;
  const int sw = n16 & 7;
  const int t = tw + n16;            // this lane's t-row for Q/K stores

#pragma unroll
  for (int nt = 0; nt < 12; nt++) {
    const ushort* wrow = WtL + (nt * 16 + n16) * 64;
    const short8 wb0 = *(short8*)(wrow + ((quad ^ sw) << 3));
    const short8 wb1 = *(short8*)(wrow + (((4 | quad) ^ sw) << 3));
    if (nt < 8) {
      // A = W rows (out-ch), B = x cols (t): C row = d quad*4+r, col = t n16
      f32x4 acc = (f32x4){0.f, 0.f, 0.f, 0.f};
      acc = __builtin_amdgcn_mfma_f32_16x16x32_bf16(wb0, xa[0], acc, 0, 0, 0);
      acc = __builtin_amdgcn_mfma_f32_16x16x32_bf16(wb1, xa[1], acc, 0, 0, 0);
      const f32x4 bv4 = *(const f32x4*)(bl + nt * 16 + quad * 4);
      uint2v pk;
      if (nt < 4) {
        const int d = nt * 16 + quad * 4;
        pk.x = pkbf((acc[0] + bv4[0]) * QSCALE, (acc[1] + bv4[1]) * QSCALE);
        pk.y = pkbf((acc[2] + bv4[2]) * QSCALE, (acc[3] + bv4[3]) * QSCALE);
        *(uint2v*)(Qws + qkbase + (size_t)t * HD + d) = pk;
      } else {
        const int d = (nt - 4) * 16 + quad * 4;
        pk.x = pkbf(acc[0] + bv4[0], acc[1] + bv4[1]);
        pk.y = pkbf(acc[2] + bv4[2], acc[3] + bv4[3]);
        *(uint2v*)(Kws + qkbase + (size_t)t * HD + d) = pk;
      }
    } else {
      // V: original order -> C row = t quad*4+r, col = d n16; store [d][t]
      f32x4 acc = (f32x4){0.f, 0.f, 0.f, 0.f};
      acc = __builtin_amdgcn_mfma_f32_16x16x32_bf16(xa[0], wb0, acc, 0, 0, 0);
      acc = __builtin_amdgcn_mfma_f32_16x16x32_bf16(xa[1], wb1, acc, 0, 0, 0);
      const float bv = bl[nt * 16 + n16];
      const int d = (nt - 8) * 16 + n16;
      const int tcol = tw + quad * 4;
      uint2v pk;
      pk.x = pkbf(acc[0] + bv, acc[1] + bv);
      pk.y = pkbf(acc[2] + bv, acc[3] + bv);
      *(uint2v*)(Vtws + (size_t)(bh * HD + d) * T_SEQ + tcol) = pk;
    }
  }
}

// ---------------------------------------------------------------------------
// Kernel 2: flash attention, R13 = R12 (32x32x16 MFMA) + bank-conflict fix.
// R12 measured SQ_LDS_BANK_CONFLICT 0 -> 4.19M: bank = f(chunk) only (128-B
// row stride is bank-invariant), and the old swizzle phys = logical ^
// (row&7) left lanes i and i+16 (same lane&7, rows 16 apart) on the SAME
// physical chunk -> same banks, different addresses -> serialization.
// Fix: fold row bit 4 into the swizzle:
//     phys_chunk = logical_chunk ^ (row & 7) ^ ((row >> 4 & 1) << 1)
// XOR is bijective per row; the DMA source pre-swizzle is the same
// self-inverse expression.  Note rows r and r+32 share (r>>4)&1, so one
// source swizzle serves both 32-row halves, and the frag reads at +2048
// shorts use the same co[].  Everything else identical to R12.
// ---------------------------------------------------------------------------
__global__ __launch_bounds__(256, 2) void flash_attn(
    const ushort* __restrict__ Qws, const ushort* __restrict__ Kws,
    const ushort* __restrict__ Vtws, float* __restrict__ out) {
  __shared__ ushort Ks[4][64 * 64];    // 32768 B: [buf][key][d], swizzled
  __shared__ ushort Vs[4][64 * 64];    // 32768 B: [buf][d][key], swizzled

  const int bx = blockIdx.x;
  const int bh = bx & 31;              // all q-tiles of bh -> same XCD (bx%8)
  const int q0 = (bx >> 5) * 128;
  const int b = bh >> 4, h = bh & 15;
  const int tid = threadIdx.x;
  const int wave = tid >> 6, lane = tid & 63;
  const int l5 = lane & 31, H = lane >> 5, swz = lane & 7;

  const ushort* Qb = Qws + (size_t)bh * T_SEQ * HD;
  const ushort* Kb = Kws + (size_t)bh * T_SEQ * HD;
  const ushort* Vb = Vtws + (size_t)bh * HD * T_SEQ;

  // Q B-frags (B of S^T = K Q^T): lane holds Q[q0+w*32+l5][dc*16+H*8+j]
  short8 qb[4];
#pragma unroll
  for (int dc = 0; dc < 4; dc++)
    qb[dc] = *(const short8*)(Qb + (size_t)(q0 + wave * 32 + l5) * HD +
                              dc * 16 + H * 8);

  // DMA staging source (thread i -> LDS byte i*16); source chunk pre-swizzled
  // with the row-bit-4-aware XOR (self-inverse).
  const int sr = tid >> 3, sp = tid & 7;
  const int sl = (sp ^ (sr & 7) ^ (((sr >> 4) & 1) << 1)) * 8;
  const ushort* pK0 = Kb + (size_t)sr * HD + sl;
  const ushort* pK1 = Kb + (size_t)(sr + 32) * HD + sl;
  const ushort* pV0 = Vb + (size_t)sr * T_SEQ + sl;
  const ushort* pV1 = Vb + (size_t)(sr + 32) * T_SEQ + sl;

  // chunk offsets for LDS frag reads: logical chunk 2i+H at row l5 (and
  // l5+32, same row-bit-4 term), row-xor swizzle incl. bit 4
  const int xr4 = ((l5 >> 4) & 1) << 1;
  int co[4];
#pragma unroll
  for (int i = 0; i < 4; i++) co[i] = ((((i << 1) | H) ^ swz ^ xr4) << 3);
  const int rbase = l5 << 6;           // row l5, 64 shorts/row

  // ones B-frag for row-sum-via-MFMA (bf16 1.0 splat)
  short8 ones;
#pragma unroll
  for (int j = 0; j < 8; j++) ones[j] = (short)0x3F80;

  f32x16 o0, o1, lA;                   // O d-tiles 0/1, l acc (rows = q)
#pragma unroll
  for (int i = 0; i < 16; i++) { o0[i] = 0.f; o1[i] = 0.f; lA[i] = 0.f; }

  // prologue: prefetch tiles 0,1 into bufs 0,1; advance pointers to tile 2
  async16(pK0, Ks[0] + wave * 512);
  async16(pK1, Ks[0] + 2048 + wave * 512);
  async16(pV0, Vs[0] + wave * 512);
  async16(pV1, Vs[0] + 2048 + wave * 512);
  async16(pK0 + 64 * HD, Ks[1] + wave * 512);
  async16(pK1 + 64 * HD, Ks[1] + 2048 + wave * 512);
  async16(pV0 + 64, Vs[1] + wave * 512);
  async16(pV1 + 64, Vs[1] + 2048 + wave * 512);
  pK0 += 128 * HD; pK1 += 128 * HD; pV0 += 128; pV1 += 128;

  for (int kt = 0; kt < 32; kt++) {
    const int cb = kt & 3;
    if (kt < 30) {
      const int pb = (kt + 2) & 3;
      async16(pK0, Ks[pb] + wave * 512);
      async16(pK1, Ks[pb] + 2048 + wave * 512);
      async16(pV0, Vs[pb] + wave * 512);
      async16(pV1, Vs[pb] + 2048 + wave * 512);
      pK0 += 64 * HD; pK1 += 64 * HD; pV0 += 64; pV1 += 64;
    }
    __builtin_amdgcn_sched_barrier(0);
    // counted drain: tile kt's 4 DMAs complete; tiles kt+1,kt+2 stay in flight
    if (kt < 30)       asm volatile("s_waitcnt vmcnt(8)" ::: "memory");
    else if (kt == 30) asm volatile("s_waitcnt vmcnt(4)" ::: "memory");
    else               asm volatile("s_waitcnt vmcnt(0)" ::: "memory");
    __builtin_amdgcn_s_barrier();
    __builtin_amdgcn_sched_barrier(0);

    const ushort* Kt = Ks[cb];
    const ushort* Vt = Vs[cb];

    // S^T = K Q^T, 32x32x16: A = K[key][d-chunk] (LDS), B = qb (regs)
    f32x16 s0, s1;
#pragma unroll
    for (int i = 0; i < 16; i++) { s0[i] = 0.f; s1[i] = 0.f; }
    __builtin_amdgcn_s_setprio(1);
#pragma unroll
    for (int dc = 0; dc < 4; dc++) {
      const short8 ka0 = *(short8*)(Kt + rbase + co[dc]);          // keys 0-31
      const short8 ka1 = *(short8*)(Kt + 2048 + rbase + co[dc]);   // keys 32-63
      s0 = __builtin_amdgcn_mfma_f32_32x32x16_bf16(ka0, qb[dc], s0, 0, 0, 0);
      s1 = __builtin_amdgcn_mfma_f32_32x32x16_bf16(ka1, qb[dc], s1, 0, 0, 0);
    }
    __builtin_amdgcn_s_setprio(0);

    // p = exp2(s); pack bf16 pairs per m-slab; route halves via pl32swap.
    // key k (rel 32-tile): reg = (k&3) + 4*((k&31)>>3), source half (k>>2)&1
    unsigned Au[2][4], Bu[2][4];
#pragma unroll
    for (int m = 0; m < 4; m++) {
      Au[0][m] = pkbf(EXP2F(s0[4 * m]),     EXP2F(s0[4 * m + 1]));
      Bu[0][m] = pkbf(EXP2F(s0[4 * m + 2]), EXP2F(s0[4 * m + 3]));
      Au[1][m] = pkbf(EXP2F(s1[4 * m]),     EXP2F(s1[4 * m + 1]));
      Bu[1][m] = pkbf(EXP2F(s1[4 * m + 2]), EXP2F(s1[4 * m + 3]));
    }
    short8 pa[4];                      // A-frag: P[q=l5][kc*16 + H*8 + j]
#pragma unroll
    for (int kc = 0; kc < 4; kc++) {
      const int kt2 = kc >> 1, mm = (kc & 1) << 1;
      uint2v sA = pl32swap(Au[kt2][mm], Au[kt2][mm + 1]);
      uint2v sB = pl32swap(Bu[kt2][mm], Bu[kt2][mm + 1]);
      union { uint4v u; short8 s; } c;
      c.u = (uint4v){sA.x, sB.x, sA.y, sB.y};
      pa[kc] = c.s;
    }

    // O += P V ; l += P 1  (A = pa regs, B = V^T slabs / ones), 32x32x16
    __builtin_amdgcn_s_setprio(1);
#pragma unroll
    for (int kc = 0; kc < 4; kc++) {
      const short8 vb0 = *(short8*)(Vt + rbase + co[kc]);          // d 0-31
      const short8 vb1 = *(short8*)(Vt + 2048 + rbase + co[kc]);   // d 32-63
      o0 = __builtin_amdgcn_mfma_f32_32x32x16_bf16(pa[kc], vb0, o0, 0, 0, 0);
      o1 = __builtin_amdgcn_mfma_f32_32x32x16_bf16(pa[kc], vb1, o1, 0, 0, 0);
      lA = __builtin_amdgcn_mfma_f32_32x32x16_bf16(pa[kc], ones, lA, 0, 0, 0);
    }
    __builtin_amdgcn_s_setprio(0);
    // no trailing barrier: NB=4, D=2 -> reuse congruences 3 (mod 4) != 0
  }

  // epilogue: reg r of o0/o1/lA all map to q-row (r&3)+8*(r>>2)+4*H
#pragma unroll
  for (int r = 0; r < 16; r++) {
    const int row = q0 + wave * 32 + (r & 3) + ((r >> 2) << 3) + (H << 2);
    const float rl = 1.0f / lA[r];
    float* op = out + (size_t)(b * T_SEQ + row) * EMBED + h * HD + l5;
    op[0]  = o0[r] * rl;
    op[32] = o1[r] * rl;
  }
}

extern "C" void kernel_launch(void* const* d_in, const int* in_sizes, int n_in,
                              void* d_out, int out_size, void* d_ws, size_t ws_size,
                              hipStream_t stream) {
  (void)in_sizes; (void)n_in; (void)out_size; (void)ws_size;
  const float* x    = (const float*)d_in[0];
  const float* W    = (const float*)d_in[1];
  const float* bias = (const float*)d_in[2];
  float* out = (float*)d_out;

  const size_t elems = (size_t)NBH * T_SEQ * HD;
  ushort* Qws  = (ushort*)d_ws;
  ushort* Kws  = Qws + elems;
  ushort* Vtws = Kws + elems;
  ushort* Wg   = Vtws + elems;       // 24576 shorts

  prep_w<<<dim3(48), dim3(256), 0, stream>>>(W, Wg);
  qkv_proj<<<dim3(1024), dim3(256), 0, stream>>>(x, Wg, bias, Qws, Kws, Vtws);
  flash_attn<<<dim3(512), dim3(256), 0, stream>>>(Qws, Kws, Vtws, out);
}

// Round 10
// 125.344 us; speedup vs baseline: 1.0032x; 1.0032x over previous
//
#include <hip/hip_runtime.h>
#include <hip/hip_bf16.h>

#define T_SEQ   2048
#define EMBED   1024
#define HD      64
#define NHEADS  16
#define NBH     32            // B*H
// 0.125 * log2(e): fold softmax scale AND exp->exp2 conversion into Q
#define QSCALE  0.18033688011112042f

typedef __attribute__((ext_vector_type(8))) short short8;
typedef __attribute__((ext_vector_type(4))) float f32x4;
typedef __attribute__((ext_vector_type(16))) float f32x16;
typedef __attribute__((ext_vector_type(2))) unsigned int uint2v;
typedef __attribute__((ext_vector_type(4))) unsigned int uint4v;

#if __has_builtin(__builtin_amdgcn_exp2f)
#define EXP2F __builtin_amdgcn_exp2f   // raw v_exp_f32
#else
#define EXP2F exp2f
#endif

// round-half-up bf16
__device__ __forceinline__ ushort bf16r(float f) {
  union { float f; unsigned u; } v; v.f = f;
  return (ushort)((v.u + 0x8000u) >> 16);
}

// pack two floats to bf16x2 (a in low half)
__device__ __forceinline__ unsigned pk2bf_perm(float a, float b) {
  union { float f; unsigned u; } ua, ub; ua.f = a; ub.f = b;
  return __builtin_amdgcn_perm(ub.u + 0x8000u, ua.u + 0x8000u, 0x07060302u);
}
#if __has_builtin(__builtin_amdgcn_cvt_pk_bf16_f32)
typedef __attribute__((ext_vector_type(2))) __bf16 bf16x2;
__device__ __forceinline__ unsigned pkbf(float a, float b) {
  union { bf16x2 v; unsigned u; } c;
  c.v = __builtin_amdgcn_cvt_pk_bf16_f32(a, b);
  return c.u;
}
#else
#define pkbf pk2bf_perm
#endif

// permlane32_swap: new_a = {a_lo, b_lo}, new_b = {a_hi, b_hi} (32-lane halves)
__device__ __forceinline__ uint2v pl32swap(unsigned a, unsigned b) {
#if __has_builtin(__builtin_amdgcn_permlane32_swap)
  return __builtin_amdgcn_permlane32_swap(a, b, false, false);
#else
  asm("v_permlane32_swap_b32 %0, %1" : "+v"(a), "+v"(b));
  return (uint2v){a, b};
#endif
}

// async 16B global->LDS DMA; HW dest = wave-uniform base + lane*16
__device__ __forceinline__ void async16(const ushort* g, ushort* l) {
  __builtin_amdgcn_global_load_lds(
      (const __attribute__((address_space(1))) unsigned int*)g,
      (__attribute__((address_space(3))) unsigned int*)l, 16, 0, 0);
}

// ---------------------------------------------------------------------------
// Kernel 0: W prep: W[d][c] fp32 -> Wg bf16 transposed [c][d], XOR-chunk
// swizzled (phys 8-short chunk = (d>>3) ^ (c&7)).
// ---------------------------------------------------------------------------
__global__ __launch_bounds__(256) void prep_w(const float* __restrict__ W,
                                              ushort* __restrict__ Wg) {
  const int i = blockIdx.x * 256 + threadIdx.x;    // 48 x 256 = 12288
  const int d = i / 192, c = i - d * 192;
  const int phys = c * 64 + (((d >> 3) ^ (c & 7)) << 3) + (d & 7);
  Wg[phys] = bf16r(W[i]);
}

// ---------------------------------------------------------------------------
// Kernel 1: QKV projection via MFMA 16x16x32 bf16 (R3 proven version).
// Q/K paths use SWAPPED operands: acc = mfma(W_frag, x_frag) so C rows =
// out-channel d, cols = t -> one 8-B store per nt + aligned f32x4 bias load.
// ---------------------------------------------------------------------------
__global__ __launch_bounds__(256) void qkv_proj(
    const float* __restrict__ x, const ushort* __restrict__ Wg,
    const float* __restrict__ bias,
    ushort* __restrict__ Qws, ushort* __restrict__ Kws,
    ushort* __restrict__ Vtws) {
  __shared__ ushort WtL[192 * 64];
  __shared__ __attribute__((aligned(16))) float bl[192];

  const int bx = blockIdx.x;         // 1024 = 2b x 16h x 32 t-tiles
  const int b  = bx >> 9;
  const int h  = (bx >> 5) & 15;
  const int t0 = (bx & 31) * 64;
  const int tid = threadIdx.x;
  const int wave = tid >> 6, lane = tid & 63;
  const int quad = lane >> 4, n16 = lane & 15;

  const int trow = t0 + wave * 16 + n16;
  const float* xr = x + ((size_t)(b * T_SEQ + trow)) * EMBED + h * HD;
  short8 xa[2];
#pragma unroll
  for (int ks = 0; ks < 2; ks++) {
    f32x4 v0 = *(const f32x4*)(xr + ks * 32 + quad * 8);
    f32x4 v1 = *(const f32x4*)(xr + ks * 32 + quad * 8 + 4);
    short8 f;
    ((unsigned*)&f)[0] = pkbf(v0[0], v0[1]);
    ((unsigned*)&f)[1] = pkbf(v0[2], v0[3]);
    ((unsigned*)&f)[2] = pkbf(v1[0], v1[1]);
    ((unsigned*)&f)[3] = pkbf(v1[2], v1[3]);
    xa[ks] = f;
  }

#pragma unroll
  for (int it = 0; it < 6; it++)
    async16(Wg + it * 2048 + tid * 8, WtL + it * 2048 + wave * 512);
  if (tid < 192) bl[tid] = bias[tid];
  __syncthreads();

  const int bh = b * NHEADS + h;
  const size_t qkbase = (size_t)bh * T_SEQ * HD;
  const int tw = t0 + wave * 16;
  const int sw = n16 & 7;
  const int t = tw + n16;            // this lane's t-row for Q/K stores

#pragma unroll
  for (int nt = 0; nt < 12; nt++) {
    const ushort* wrow = WtL + (nt * 16 + n16) * 64;
    const short8 wb0 = *(short8*)(wrow + ((quad ^ sw) << 3));
    const short8 wb1 = *(short8*)(wrow + (((4 | quad) ^ sw) << 3));
    if (nt < 8) {
      // A = W rows (out-ch), B = x cols (t): C row = d quad*4+r, col = t n16
      f32x4 acc = (f32x4){0.f, 0.f, 0.f, 0.f};
      acc = __builtin_amdgcn_mfma_f32_16x16x32_bf16(wb0, xa[0], acc, 0, 0, 0);
      acc = __builtin_amdgcn_mfma_f32_16x16x32_bf16(wb1, xa[1], acc, 0, 0, 0);
      const f32x4 bv4 = *(const f32x4*)(bl + nt * 16 + quad * 4);
      uint2v pk;
      if (nt < 4) {
        const int d = nt * 16 + quad * 4;
        pk.x = pkbf((acc[0] + bv4[0]) * QSCALE, (acc[1] + bv4[1]) * QSCALE);
        pk.y = pkbf((acc[2] + bv4[2]) * QSCALE, (acc[3] + bv4[3]) * QSCALE);
        *(uint2v*)(Qws + qkbase + (size_t)t * HD + d) = pk;
      } else {
        const int d = (nt - 4) * 16 + quad * 4;
        pk.x = pkbf(acc[0] + bv4[0], acc[1] + bv4[1]);
        pk.y = pkbf(acc[2] + bv4[2], acc[3] + bv4[3]);
        *(uint2v*)(Kws + qkbase + (size_t)t * HD + d) = pk;
      }
    } else {
      // V: original order -> C row = t quad*4+r, col = d n16; store [d][t]
      f32x4 acc = (f32x4){0.f, 0.f, 0.f, 0.f};
      acc = __builtin_amdgcn_mfma_f32_16x16x32_bf16(xa[0], wb0, acc, 0, 0, 0);
      acc = __builtin_amdgcn_mfma_f32_16x16x32_bf16(xa[1], wb1, acc, 0, 0, 0);
      const float bv = bl[nt * 16 + n16];
      const int d = (nt - 8) * 16 + n16;
      const int tcol = tw + quad * 4;
      uint2v pk;
      pk.x = pkbf(acc[0] + bv, acc[1] + bv);
      pk.y = pkbf(acc[2] + bv, acc[3] + bv);
      *(uint2v*)(Vtws + (size_t)(bh * HD + d) * T_SEQ + tcol) = pk;
    }
  }
}

// ---------------------------------------------------------------------------
// Kernel 2: flash attention, R15 = R14 pipeline with RACE-FIXED DMA placement.
// R14 FAILED (absmax 2e-2): it kept R13's issue-DMA-BEFORE-barrier order, so
// the DMA into buf (kt+3)%4 = (kt-1)%4 issued by fast waves in window
// (barrier kt, barrier kt+1) overwrote V[(kt-1)%4] while slow waves were
// still reading it in smpv(kt-1) -- same window, no ordering.
// FIX: issue the DMA AFTER the barrier.  Per iter kt:
//   {vmcnt wait -> s_barrier -> issue DMA(kt+2) -> QK(kt) -> smpv(kt-1)}
// Writes into (kt+2)%4=(kt-2)%4 are now barrier-kt-ordered after the last
// readers (smpv(kt-2), window ending at barrier kt).  Same-window buffers
// {(kt+2)%4 W, kt%4 R, (kt-1)%4 R} pairwise distinct mod 4.  Tile kt is
// still issued 2 iterations ahead (in iter kt-2); at the wait only tile
// kt+1 is also outstanding -> vmcnt(4) steady, vmcnt(0) at kt=31.
// Cross-iteration softmax pipeline (the R14 goal, unchanged): each iter
// overlaps QK-MFMA(kt) with exp2+pack+PV of tile kt-1 -- independent dep
// chains on separate pipes, hiding the serial QK->exp2->PV chain that
// capped R13 at 52.5 us / MfmaUtil 33%.  Ping-pong sA/sB (rule #20).
// Numerics identical to R13 per tile.
// ---------------------------------------------------------------------------
__global__ __launch_bounds__(256, 2) void flash_attn(
    const ushort* __restrict__ Qws, const ushort* __restrict__ Kws,
    const ushort* __restrict__ Vtws, float* __restrict__ out) {
  __shared__ ushort Ks[4][64 * 64];    // 32768 B: [buf][key][d], swizzled
  __shared__ ushort Vs[4][64 * 64];    // 32768 B: [buf][d][key], swizzled

  const int bx = blockIdx.x;
  const int bh = bx & 31;              // all q-tiles of bh -> same XCD (bx%8)
  const int q0 = (bx >> 5) * 128;
  const int b = bh >> 4, h = bh & 15;
  const int tid = threadIdx.x;
  const int wave = tid >> 6, lane = tid & 63;
  const int l5 = lane & 31, H = lane >> 5, swz = lane & 7;

  const ushort* Qb = Qws + (size_t)bh * T_SEQ * HD;
  const ushort* Kb = Kws + (size_t)bh * T_SEQ * HD;
  const ushort* Vb = Vtws + (size_t)bh * HD * T_SEQ;

  // Q B-frags (B of S^T = K Q^T): lane holds Q[q0+w*32+l5][dc*16+H*8+j]
  short8 qb[4];
#pragma unroll
  for (int dc = 0; dc < 4; dc++)
    qb[dc] = *(const short8*)(Qb + (size_t)(q0 + wave * 32 + l5) * HD +
                              dc * 16 + H * 8);

  // DMA staging source (thread i -> LDS byte i*16); source chunk pre-swizzled
  // (row-bit-4-aware XOR, self-inverse; matches read-side co[]).
  const int sr = tid >> 3, sp = tid & 7;
  const int sl = (sp ^ (sr & 7) ^ (((sr >> 4) & 1) << 1)) * 8;
  const ushort* pK0 = Kb + (size_t)sr * HD + sl;
  const ushort* pK1 = Kb + (size_t)(sr + 32) * HD + sl;
  const ushort* pV0 = Vb + (size_t)sr * T_SEQ + sl;
  const ushort* pV1 = Vb + (size_t)(sr + 32) * T_SEQ + sl;

  // chunk offsets for LDS frag reads: logical chunk 2i+H at row l5,
  // row-xor swizzle incl. bit 4
  const int xr4 = ((l5 >> 4) & 1) << 1;
  int co[4];
#pragma unroll
  for (int i = 0; i < 4; i++) co[i] = ((((i << 1) | H) ^ swz ^ xr4) << 3);
  const int rbase = l5 << 6;           // row l5, 64 shorts/row

  // ones B-frag for row-sum-via-MFMA (bf16 1.0 splat)
  short8 ones;
#pragma unroll
  for (int j = 0; j < 8; j++) ones[j] = (short)0x3F80;

  f32x16 o0, o1, lA;                   // O d-tiles 0/1, l acc (rows = q)
#pragma unroll
  for (int i = 0; i < 16; i++) { o0[i] = 0.f; o1[i] = 0.f; lA[i] = 0.f; }

  // ---- QK stage for tile kt: wait(tile kt), barrier, issue DMA(kt+2),
  //      then S^T = K Q^T from Ks[kt%4]
  auto qk = [&](int kt, f32x16& d0, f32x16& d1) {
    __builtin_amdgcn_sched_barrier(0);
    if (kt < 31) asm volatile("s_waitcnt vmcnt(4)" ::: "memory");
    else         asm volatile("s_waitcnt vmcnt(0)" ::: "memory");
    __builtin_amdgcn_s_barrier();
    if (kt < 30) {                     // issue AFTER barrier (race fix)
      const int pb = (kt + 2) & 3;
      async16(pK0, Ks[pb] + wave * 512);
      async16(pK1, Ks[pb] + 2048 + wave * 512);
      async16(pV0, Vs[pb] + wave * 512);
      async16(pV1, Vs[pb] + 2048 + wave * 512);
      pK0 += 64 * HD; pK1 += 64 * HD; pV0 += 64; pV1 += 64;
    }
    __builtin_amdgcn_sched_barrier(0);

    const ushort* Kt = Ks[kt & 3];
#pragma unroll
    for (int i = 0; i < 16; i++) { d0[i] = 0.f; d1[i] = 0.f; }
    __builtin_amdgcn_s_setprio(1);
#pragma unroll
    for (int dc = 0; dc < 4; dc++) {
      const short8 ka0 = *(short8*)(Kt + rbase + co[dc]);          // keys 0-31
      const short8 ka1 = *(short8*)(Kt + 2048 + rbase + co[dc]);   // keys 32-63
      d0 = __builtin_amdgcn_mfma_f32_32x32x16_bf16(ka0, qb[dc], d0, 0, 0, 0);
      d1 = __builtin_amdgcn_mfma_f32_32x32x16_bf16(ka1, qb[dc], d1, 0, 0, 0);
    }
    __builtin_amdgcn_s_setprio(0);
  };

  // ---- softmax + PV stage for tile kt (s of that tile in s0r/s1r)
  auto smpv = [&](int kt, const f32x16& s0r, const f32x16& s1r) {
    const ushort* Vt = Vs[kt & 3];
    // p = exp2(s); pack bf16 pairs per m-slab; route halves via pl32swap.
    unsigned Au[2][4], Bu[2][4];
#pragma unroll
    for (int m = 0; m < 4; m++) {
      Au[0][m] = pkbf(EXP2F(s0r[4 * m]),     EXP2F(s0r[4 * m + 1]));
      Bu[0][m] = pkbf(EXP2F(s0r[4 * m + 2]), EXP2F(s0r[4 * m + 3]));
      Au[1][m] = pkbf(EXP2F(s1r[4 * m]),     EXP2F(s1r[4 * m + 1]));
      Bu[1][m] = pkbf(EXP2F(s1r[4 * m + 2]), EXP2F(s1r[4 * m + 3]));
    }
    short8 pa[4];                      // A-frag: P[q=l5][kc*16 + H*8 + j]
#pragma unroll
    for (int kc = 0; kc < 4; kc++) {
      const int kt2 = kc >> 1, mm = (kc & 1) << 1;
      uint2v sA = pl32swap(Au[kt2][mm], Au[kt2][mm + 1]);
      uint2v sB = pl32swap(Bu[kt2][mm], Bu[kt2][mm + 1]);
      union { uint4v u; short8 s; } c;
      c.u = (uint4v){sA.x, sB.x, sA.y, sB.y};
      pa[kc] = c.s;
    }
    __builtin_amdgcn_s_setprio(1);
#pragma unroll
    for (int kc = 0; kc < 4; kc++) {
      const short8 vb0 = *(short8*)(Vt + rbase + co[kc]);          // d 0-31
      const short8 vb1 = *(short8*)(Vt + 2048 + rbase + co[kc]);   // d 32-63
      o0 = __builtin_amdgcn_mfma_f32_32x32x16_bf16(pa[kc], vb0, o0, 0, 0, 0);
      o1 = __builtin_amdgcn_mfma_f32_32x32x16_bf16(pa[kc], vb1, o1, 0, 0, 0);
      lA = __builtin_amdgcn_mfma_f32_32x32x16_bf16(pa[kc], ones, lA, 0, 0, 0);
    }
    __builtin_amdgcn_s_setprio(0);
  };

  // prologue: prefetch tiles 0,1 into bufs 0,1; advance pointers to tile 2
  async16(pK0, Ks[0] + wave * 512);
  async16(pK1, Ks[0] + 2048 + wave * 512);
  async16(pV0, Vs[0] + wave * 512);
  async16(pV1, Vs[0] + 2048 + wave * 512);
  async16(pK0 + 64 * HD, Ks[1] + wave * 512);
  async16(pK1 + 64 * HD, Ks[1] + 2048 + wave * 512);
  async16(pV0 + 64, Vs[1] + wave * 512);
  async16(pV1 + 64, Vs[1] + 2048 + wave * 512);
  pK0 += 128 * HD; pK1 += 128 * HD; pV0 += 128; pV1 += 128;

  // pipelined main: QK(kt) overlaps exp2+PV of tile kt-1 (ping-pong sA/sB)
  f32x16 sA0, sA1, sB0, sB1;
  qk(0, sA0, sA1);
  for (int kt = 1; kt < 31; kt += 2) {
    qk(kt, sB0, sB1);
    smpv(kt - 1, sA0, sA1);
    qk(kt + 1, sA0, sA1);
    smpv(kt, sB0, sB1);
  }
  qk(31, sB0, sB1);
  smpv(30, sA0, sA1);
  smpv(31, sB0, sB1);

  // epilogue: reg r of o0/o1/lA all map to q-row (r&3)+8*(r>>2)+4*H
#pragma unroll
  for (int r = 0; r < 16; r++) {
    const int row = q0 + wave * 32 + (r & 3) + ((r >> 2) << 3) + (H << 2);
    const float rl = 1.0f / lA[r];
    float* op = out + (size_t)(b * T_SEQ + row) * EMBED + h * HD + l5;
    op[0]  = o0[r] * rl;
    op[32] = o1[r] * rl;
  }
}

extern "C" void kernel_launch(void* const* d_in, const int* in_sizes, int n_in,
                              void* d_out, int out_size, void* d_ws, size_t ws_size,
                              hipStream_t stream) {
  (void)in_sizes; (void)n_in; (void)out_size; (void)ws_size;
  const float* x    = (const float*)d_in[0];
  const float* W    = (const float*)d_in[1];
  const float* bias = (const float*)d_in[2];
  float* out = (float*)d_out;

  const size_t elems = (size_t)NBH * T_SEQ * HD;
  ushort* Qws  = (ushort*)d_ws;
  ushort* Kws  = Qws + elems;
  ushort* Vtws = Kws + elems;
  ushort* Wg   = Vtws + elems;       // 24576 shorts

  prep_w<<<dim3(48), dim3(256), 0, stream>>>(W, Wg);
  qkv_proj<<<dim3(1024), dim3(256), 0, stream>>>(x, Wg, bias, Qws, Kws, Vtws);
  flash_attn<<<dim3(512), dim3(256), 0, stream>>>(Qws, Kws, Vtws, out);
}